// Round 1
// 236.172 us; speedup vs baseline: 1.0336x; 1.0336x over previous
//
#include <hip/hip_runtime.h>

typedef float f32x2 __attribute__((ext_vector_type(2)));

#define IMG_W 512
#define IMG_H 512
#define TY 8
#define PLANES 96              // N*C = 32*3
#define NPIX (32ll * 3 * 512 * 512)
#define NACC 64                // atomic fanout slots

// Separable Gaussian, sigma=1.5, size=11, normalized (compile-time folded).
#define WG_INIT { 0.00102838f, 0.00759876f, 0.03600077f, 0.10936069f, \
                  0.21300553f, 0.26601172f, 0.21300553f, 0.10936069f, \
                  0.03600077f, 0.00759876f, 0.00102838f }

// 4 maps instead of 5: SSIM only needs sigma1_sq + sigma2_sq as a SUM, and
// conv is linear -> convolve {p, t, p*p + t*t, p*t}. (R3: -20% LDS + VALU)
// LDS: 8 slabs (4 maps x 2 row-pair) x 264 atoms x 16 B = 33792 B -> 4 blocks/CU.
// Entry e (e=0..527) = f32x2{row 2rp, row 2rp+1} at padded col e (data col e-8).
// Atom at = e>>1 holds entries 2at,2at+1. XOR swizzle ap = at ^ ((at>>3)&7):
// horizontal reads (lane g -> atoms g+1..g+7) conflict-free, writes 2-way (free).
#define NMAPS 5   // historical; active maps below
#define SLAB_ATOMS 264
#define SLAB_BYTES (SLAB_ATOMS * 16)

__device__ __forceinline__ int swz(int at) { return at ^ ((at >> 3) & 7); }

__global__ __launch_bounds__(512)   // NO min-waves arg: (512,4) forced a 64-VGPR
                                    // cap and 393 MB of spill in R2 (measured)
void ssim_main(const float* __restrict__ pred, const float* __restrict__ targ,
               double* __restrict__ acc) {
    const float WG[11] = WG_INIT;

    __shared__ __align__(16) unsigned char ldsraw[8 * SLAB_BYTES];
    __shared__ float wsum[8];

    const int tid   = threadIdx.x;
    const int x     = tid;                 // column owned in vertical pass
    const int plane = blockIdx.y;
    const int y0    = blockIdx.x * TY;
    const size_t base = (size_t)plane * (IMG_W * IMG_H);
    const float* pCol = pred + base + x;
    const float* tCol = targ + base + x;

    // Zero horizontal halo pads: atoms 0..3 and 260..263 in each of 8 slabs.
    // Data writes never touch them; they stay zero across both halves.
    if (tid < 64) {
        const int s   = tid >> 3;               // slab 0..7
        const int idx = tid & 7;                // 0..7
        const int at  = (idx < 4) ? idx : (256 + idx);   // 0..3 / 260..263
        *(float4*)(ldsraw + s * SLAB_BYTES + swz(at) * 16) =
            (float4){0.f, 0.f, 0.f, 0.f};
    }

    // ---- vertical pass: 18 rows -> 8 output rows as 4 packed row-pairs ----
    float pv[TY + 10], tv[TY + 10];
#pragma unroll
    for (int iy = 0; iy < TY + 10; ++iy) {
        const int y = y0 - 5 + iy;
        pv[iy] = 0.f; tv[iy] = 0.f;
        if ((unsigned)y < (unsigned)IMG_H) {    // wave-uniform
            pv[iy] = pCol[(size_t)y * IMG_W];
            tv[iy] = tCol[(size_t)y * IMG_W];
        }
    }

    f32x2 A[4][4];
#pragma unroll
    for (int m = 0; m < 4; ++m)
#pragma unroll
        for (int rp = 0; rp < 4; ++rp) A[m][rp] = (f32x2){0.f, 0.f};

#pragma unroll
    for (int iy = 0; iy < TY + 10; ++iy) {
        const float p = pv[iy], t = tv[iy];
        const float ss = __builtin_fmaf(t, t, p * p);   // p^2 + t^2
        const float pt = p * t;
        const f32x2 vs[4] = { {p,p}, {t,t}, {ss,ss}, {pt,pt} };
#pragma unroll
        for (int rp = 0; rp < 4; ++rp) {
            const int a = iy - 2 * rp;                      // compile-time
            if (a < 0 || a > 11) continue;                  // both lanes zero
            const float w0 = (a <= 10) ? WG[a] : 0.f;       // row 2rp
            const float w1 = (a >= 1)  ? WG[a - 1] : 0.f;   // row 2rp+1
            const f32x2 w = (f32x2){w0, w1};
#pragma unroll
            for (int m = 0; m < 4; ++m)
                A[m][rp] = __builtin_elementwise_fma(vs[m], w, A[m][rp]);
        }
    }

    // ---- horizontal pass + SSIM, two 4-row halves through LDS ----
    const float C1 = 1e-4f, C2 = 9e-4f;
    float lsum = 0.f;
    const int rpl = tid >> 8;          // 0..1: slab this thread reads
    const int g   = tid & 255;         // col group: packed out-cols 2g, 2g+1
    // write address: entry c = x+8
    const int wat = (x + 8) >> 1;
    const int wof = swz(wat) * 16 + ((x + 8) & 1) * 8;

#pragma unroll
    for (int half = 0; half < 2; ++half) {
        __syncthreads();   // pads ready (1st) / previous half consumed (2nd)
#pragma unroll
        for (int m = 0; m < 4; ++m)
#pragma unroll
            for (int rl = 0; rl < 2; ++rl)
                *(f32x2*)(ldsraw + (m * 2 + rl) * SLAB_BYTES + wof) =
                    A[m][2 * half + rl];
        __syncthreads();

        // out cols 2g,2g+1 need entries 2g+3..2g+14 -> atoms g+1..g+7.
        f32x2 H[4][2];
#pragma unroll
        for (int m = 0; m < 4; ++m) {
            const unsigned char* slab = ldsraw + (m * 2 + rpl) * SLAB_BYTES;
            f32x2 win[14];
#pragma unroll
            for (int q = 0; q < 7; ++q) {
                const float4 v = *(const float4*)(slab + swz(g + 1 + q) * 16);
                win[2*q]   = (f32x2){v.x, v.y};
                win[2*q+1] = (f32x2){v.z, v.w};
            }
            f32x2 h0 = (f32x2){0.f, 0.f}, h1 = (f32x2){0.f, 0.f};
#pragma unroll
            for (int k = 0; k < 11; ++k) {
                const f32x2 wk = (f32x2){WG[k], WG[k]};
                h0 = __builtin_elementwise_fma(win[1 + k], wk, h0);
                h1 = __builtin_elementwise_fma(win[2 + k], wk, h1);
            }
            H[m][0] = h0; H[m][1] = h1;
        }

#pragma unroll
        for (int c = 0; c < 2; ++c) {
            const f32x2 mu1 = H[0][c], mu2 = H[1][c];
            const f32x2 S   = H[2][c], P  = H[3][c];
            const f32x2 mu12 = mu1 * mu2;
            const f32x2 musq = mu1 * mu1 + mu2 * mu2;
            // num = (2*mu1mu2 + C1) * (2*sigma12 + C2), sigma12 = P - mu12
            const f32x2 num = (mu12 + mu12 + (f32x2){C1, C1}) *
                              ((P - mu12) + (P - mu12) + (f32x2){C2, C2});
            // den = (mu1^2+mu2^2 + C1) * (sig1+sig2 + C2) + 1e-8,
            //       sig1+sig2 = S - musq
            const f32x2 den = (musq + (f32x2){C1, C1}) *
                              (S - musq + (f32x2){C2, C2}) + (f32x2){1e-8f, 1e-8f};
            lsum += num.x * __builtin_amdgcn_rcpf(den.x);
            lsum += num.y * __builtin_amdgcn_rcpf(den.y);
        }
    }

    // ---- reduction: wave shuffle -> LDS -> one atomic per block (64 slots) ----
#pragma unroll
    for (int off = 32; off > 0; off >>= 1)
        lsum += __shfl_down(lsum, off);
    if ((tid & 63) == 0) wsum[tid >> 6] = lsum;
    __syncthreads();
    if (tid == 0) {
        float s = 0.f;
#pragma unroll
        for (int i = 0; i < 8; ++i) s += wsum[i];
        atomicAdd(&acc[blockIdx.x & (NACC - 1)], (double)s);
    }
}

__global__ void ssim_final(const double* __restrict__ acc, float* __restrict__ out) {
    double s = 0.0;
#pragma unroll
    for (int i = 0; i < NACC; ++i) s += acc[i];
    out[0] = 1.0f - (float)(s * (1.0 / (double)NPIX));
}

extern "C" void kernel_launch(void* const* d_in, const int* in_sizes, int n_in,
                              void* d_out, int out_size, void* d_ws, size_t ws_size,
                              hipStream_t stream) {
    const float* pred = (const float*)d_in[0];
    const float* targ = (const float*)d_in[1];
    double* acc = (double*)d_ws;

    hipMemsetAsync(acc, 0, NACC * sizeof(double), stream);

    dim3 grid(IMG_H / TY, PLANES);   // adjacent strips -> halo L2 reuse (R1: 219 MB)
    ssim_main<<<grid, 512, 0, stream>>>(pred, targ, acc);
    ssim_final<<<1, 1, 0, stream>>>(acc, (float*)d_out);
}

// Round 2
// 233.168 us; speedup vs baseline: 1.0470x; 1.0129x over previous
//
#include <hip/hip_runtime.h>

typedef float f32x2 __attribute__((ext_vector_type(2)));

#define IMG_W 512
#define IMG_H 512
#define TY 8
#define PLANES 96              // N*C = 32*3
#define NPIX (32ll * 3 * 512 * 512)
#define NACC 64                // atomic fanout slots

// Separable Gaussian, sigma=1.5, size=11, normalized (compile-time folded).
#define WG_INIT { 0.00102838f, 0.00759876f, 0.03600077f, 0.10936069f, \
                  0.21300553f, 0.26601172f, 0.21300553f, 0.10936069f, \
                  0.03600077f, 0.00759876f, 0.00102838f }

// 4 maps {p, t, p^2+t^2, p*t} (sigma1+sigma2 fused via conv linearity, R3).
// R4: horizontal pass re-tiled — 512 threads = 4 row-pair slabs x 128 col
// groups, each thread produces 4 output cols from an 8-atom window
// (atoms 2g+1..2g+8). Read amortization: 56 -> 32 ds_read_b128/thread.
// The 4 maps stream through the SAME 8 slabs in two phases (maps 0,1 then
// 2,3) to stay under the 64 KB static-LDS limit (8 x 4224 = 33792 B).
// Entry e (e=0..527) = f32x2{row 2rp, row 2rp+1} at padded col e (data col
// e-8). Atom at = e>>1. XOR swizzle at^((at>>3)&7): stride-2 64-lane reads
// span 128 consecutive atoms -> every bank-group hit exactly 8x (even);
// writes 32 consecutive atoms, 2 lanes/atom -> even. Conflict-free.
#define SLAB_ATOMS 264
#define SLAB_BYTES (SLAB_ATOMS * 16)

__device__ __forceinline__ int swz(int at) { return at ^ ((at >> 3) & 7); }

__global__ __launch_bounds__(512)   // NO min-waves arg: (512,4) forced a 64-VGPR
                                    // cap and 393 MB of spill in R2 (measured)
void ssim_main(const float* __restrict__ pred, const float* __restrict__ targ,
               double* __restrict__ acc) {
    const float WG[11] = WG_INIT;

    __shared__ __align__(16) unsigned char ldsraw[8 * SLAB_BYTES];
    __shared__ float wsum[8];

    const int tid   = threadIdx.x;
    const int x     = tid;                 // column owned in vertical pass
    const int plane = blockIdx.y;
    const int y0    = blockIdx.x * TY;
    const size_t base = (size_t)plane * (IMG_W * IMG_H);
    const float* pCol = pred + base + x;
    const float* tCol = targ + base + x;

    // Zero horizontal halo pads: atoms 0..3 and 260..263 in each of 8 slabs.
    // Data writes never touch them; they stay zero across both phases.
    if (tid < 64) {
        const int s   = tid >> 3;               // slab 0..7
        const int idx = tid & 7;                // 0..7
        const int at  = (idx < 4) ? idx : (256 + idx);   // 0..3 / 260..263
        *(float4*)(ldsraw + s * SLAB_BYTES + swz(at) * 16) =
            (float4){0.f, 0.f, 0.f, 0.f};
    }

    // ---- vertical pass: 18 rows -> 8 output rows as 4 packed row-pairs ----
    float pv[TY + 10], tv[TY + 10];
#pragma unroll
    for (int iy = 0; iy < TY + 10; ++iy) {
        const int y = y0 - 5 + iy;
        pv[iy] = 0.f; tv[iy] = 0.f;
        if ((unsigned)y < (unsigned)IMG_H) {    // wave-uniform
            pv[iy] = pCol[(size_t)y * IMG_W];
            tv[iy] = tCol[(size_t)y * IMG_W];
        }
    }

    f32x2 A[4][4];
#pragma unroll
    for (int m = 0; m < 4; ++m)
#pragma unroll
        for (int rp = 0; rp < 4; ++rp) A[m][rp] = (f32x2){0.f, 0.f};

#pragma unroll
    for (int iy = 0; iy < TY + 10; ++iy) {
        const float p = pv[iy], t = tv[iy];
        const float ss = __builtin_fmaf(t, t, p * p);   // p^2 + t^2
        const float pt = p * t;
        const f32x2 vs[4] = { {p,p}, {t,t}, {ss,ss}, {pt,pt} };
#pragma unroll
        for (int rp = 0; rp < 4; ++rp) {
            const int a = iy - 2 * rp;                      // compile-time
            if (a < 0 || a > 11) continue;                  // both lanes zero
            const float w0 = (a <= 10) ? WG[a] : 0.f;       // row 2rp
            const float w1 = (a >= 1)  ? WG[a - 1] : 0.f;   // row 2rp+1
            const f32x2 w = (f32x2){w0, w1};
#pragma unroll
            for (int m = 0; m < 4; ++m)
                A[m][rp] = __builtin_elementwise_fma(vs[m], w, A[m][rp]);
        }
    }

    // ---- horizontal pass: thread (rpl, g) -> out cols 4g..4g+3, row-pair rpl
    const int g   = tid & 127;         // col group
    const int rpl = tid >> 7;          // 0..3: row-pair slab this thread reads
    // write address: entry c = x+8
    const int wat = (x + 8) >> 1;
    const int wof = swz(wat) * 16 + ((x + 8) & 1) * 8;
    // read addresses: atoms 2g+1..2g+8 -> entries 4g+2..4g+17 (win[0..15]);
    // out col 4g+c needs entries 4g+c+3..4g+c+13 = win[c+1..c+11]
    int rof[8];
#pragma unroll
    for (int q = 0; q < 8; ++q) rof[q] = swz(2 * g + 1 + q) * 16;

    f32x2 H[4][4];   // [map][col]
#pragma unroll
    for (int phase = 0; phase < 2; ++phase) {
        if (phase) __syncthreads();   // phase-0 reads done before overwrite
#pragma unroll
        for (int ml = 0; ml < 2; ++ml)
#pragma unroll
            for (int rp = 0; rp < 4; ++rp)
                *(f32x2*)(ldsraw + (ml * 4 + rp) * SLAB_BYTES + wof) =
                    A[phase * 2 + ml][rp];
        __syncthreads();              // also covers pad-zero init (phase 0)

#pragma unroll
        for (int ml = 0; ml < 2; ++ml) {
            const unsigned char* slab = ldsraw + (ml * 4 + rpl) * SLAB_BYTES;
            f32x2 win[16];
#pragma unroll
            for (int q = 0; q < 8; ++q) {
                const float4 v = *(const float4*)(slab + rof[q]);
                win[2 * q]     = (f32x2){v.x, v.y};
                win[2 * q + 1] = (f32x2){v.z, v.w};
            }
#pragma unroll
            for (int c = 0; c < 4; ++c) {
                f32x2 h = (f32x2){0.f, 0.f};
#pragma unroll
                for (int k = 0; k < 11; ++k) {
                    const f32x2 wk = (f32x2){WG[k], WG[k]};
                    h = __builtin_elementwise_fma(win[c + 1 + k], wk, h);
                }
                H[phase * 2 + ml][c] = h;
            }
        }
    }

    // ---- SSIM on 4 cols x 2 rows ----
    const float C1 = 1e-4f, C2 = 9e-4f;
    float lsum = 0.f;
#pragma unroll
    for (int c = 0; c < 4; ++c) {
        const f32x2 mu1 = H[0][c], mu2 = H[1][c];
        const f32x2 S   = H[2][c], P  = H[3][c];
        const f32x2 mu12 = mu1 * mu2;
        const f32x2 musq = mu1 * mu1 + mu2 * mu2;
        // num = (2*mu1mu2 + C1) * (2*sigma12 + C2), sigma12 = P - mu12
        const f32x2 num = (mu12 + mu12 + (f32x2){C1, C1}) *
                          ((P - mu12) + (P - mu12) + (f32x2){C2, C2});
        // den = (musq + C1) * (S - musq + C2) + 1e-8
        const f32x2 den = (musq + (f32x2){C1, C1}) *
                          (S - musq + (f32x2){C2, C2}) + (f32x2){1e-8f, 1e-8f};
        lsum += num.x * __builtin_amdgcn_rcpf(den.x);
        lsum += num.y * __builtin_amdgcn_rcpf(den.y);
    }

    // ---- reduction: wave shuffle -> LDS -> one atomic per block (64 slots) ----
#pragma unroll
    for (int off = 32; off > 0; off >>= 1)
        lsum += __shfl_down(lsum, off);
    if ((tid & 63) == 0) wsum[tid >> 6] = lsum;
    __syncthreads();
    if (tid == 0) {
        float s = 0.f;
#pragma unroll
        for (int i = 0; i < 8; ++i) s += wsum[i];
        atomicAdd(&acc[blockIdx.x & (NACC - 1)], (double)s);
    }
}

__global__ void ssim_final(const double* __restrict__ acc, float* __restrict__ out) {
    double s = 0.0;
#pragma unroll
    for (int i = 0; i < NACC; ++i) s += acc[i];
    out[0] = 1.0f - (float)(s * (1.0 / (double)NPIX));
}

extern "C" void kernel_launch(void* const* d_in, const int* in_sizes, int n_in,
                              void* d_out, int out_size, void* d_ws, size_t ws_size,
                              hipStream_t stream) {
    const float* pred = (const float*)d_in[0];
    const float* targ = (const float*)d_in[1];
    double* acc = (double*)d_ws;

    hipMemsetAsync(acc, 0, NACC * sizeof(double), stream);

    dim3 grid(IMG_H / TY, PLANES);   // adjacent strips -> halo L2 reuse (R1: 219 MB)
    ssim_main<<<grid, 512, 0, stream>>>(pred, targ, acc);
    ssim_final<<<1, 1, 0, stream>>>(acc, (float*)d_out);
}

// Round 3
// 222.565 us; speedup vs baseline: 1.0968x; 1.0476x over previous
//
#include <hip/hip_runtime.h>

typedef float f32x2 __attribute__((ext_vector_type(2)));

#define IMG_W 512
#define IMG_H 512
#define TY 8
#define PLANES 96              // N*C = 32*3
#define NPIX (32ll * 3 * 512 * 512)
#define NACC 64                // atomic fanout slots

// Separable Gaussian, sigma=1.5, size=11, normalized (compile-time folded).
#define WG_INIT { 0.00102838f, 0.00759876f, 0.03600077f, 0.10936069f, \
                  0.21300553f, 0.26601172f, 0.21300553f, 0.10936069f, \
                  0.03600077f, 0.00759876f, 0.00102838f }

// 4 maps {p, t, p^2+t^2, p*t} (sigma1+sigma2 fused via conv linearity, R3).
// Horizontal pass tiled 4 cols/thread (R4): 512 threads = 4 row-pair slabs x
// 128 col groups; thread reads atoms 2g+1..2g+8 (16 entries) -> 32 ds_read_b128
// total. Maps stream through 8 slabs in two phases (maps 0,1 then 2,3).
//
// R5 layout fix: R4's reads are CROSS-LANE STRIDE-2 in atoms; the old swizzle
// at^((at>>3)&7) is only even for stride-1 -> conflicts UP 1.10e7->1.18e7
// (measured). New positional remap, bank-group(at) = ((at>>1)&7) ^ ((at&1)<<2):
//  - reads  (b128, 8 lanes/cyc): atoms 2l+c, parity const -> (at>>1)&7 covers
//    all 8 groups once per 8-lane cycle. Conflict-free.
//  - writes (b64, 16 lanes/cyc): 8 consecutive atoms from even base; pairs
//    (a,a+1) share at>>1 but parity XOR4 splits -> all 8 groups. Conflict-free.
// Slab padded to 272 atoms (17 full 16-atom blocks) so the remap is in-range.
#define SLAB_ATOMS 272
#define SLAB_BYTES (SLAB_ATOMS * 16)

__device__ __forceinline__ int pmap(int at) {
    const int par = at & 1;
    return (at & ~15) | (par << 3) | (((at >> 1) & 7) ^ (par << 2));
}

__global__ __launch_bounds__(512)   // NO min-waves arg: (512,4) forced a 64-VGPR
                                    // cap and 393 MB of spill in R2 (measured)
void ssim_main(const float* __restrict__ pred, const float* __restrict__ targ,
               double* __restrict__ acc) {
    const float WG[11] = WG_INIT;

    __shared__ __align__(16) unsigned char ldsraw[8 * SLAB_BYTES];
    __shared__ float wsum[8];

    const int tid   = threadIdx.x;
    const int x     = tid;                 // column owned in vertical pass
    const int plane = blockIdx.y;
    const int y0    = blockIdx.x * TY;
    const size_t base = (size_t)plane * (IMG_W * IMG_H);
    const float* pCol = pred + base + x;
    const float* tCol = targ + base + x;

    // Zero horizontal halo pads: atoms 0..3 and 260..263 in each of 8 slabs.
    // Data writes never touch them; they stay zero across both phases.
    if (tid < 64) {
        const int s   = tid >> 3;               // slab 0..7
        const int idx = tid & 7;                // 0..7
        const int at  = (idx < 4) ? idx : (256 + idx);   // 0..3 / 260..263
        *(float4*)(ldsraw + s * SLAB_BYTES + pmap(at) * 16) =
            (float4){0.f, 0.f, 0.f, 0.f};
    }

    // ---- vertical pass: 18 rows -> 8 output rows as 4 packed row-pairs ----
    float pv[TY + 10], tv[TY + 10];
#pragma unroll
    for (int iy = 0; iy < TY + 10; ++iy) {
        const int y = y0 - 5 + iy;
        pv[iy] = 0.f; tv[iy] = 0.f;
        if ((unsigned)y < (unsigned)IMG_H) {    // wave-uniform
            pv[iy] = pCol[(size_t)y * IMG_W];
            tv[iy] = tCol[(size_t)y * IMG_W];
        }
    }

    f32x2 A[4][4];
#pragma unroll
    for (int m = 0; m < 4; ++m)
#pragma unroll
        for (int rp = 0; rp < 4; ++rp) A[m][rp] = (f32x2){0.f, 0.f};

#pragma unroll
    for (int iy = 0; iy < TY + 10; ++iy) {
        const float p = pv[iy], t = tv[iy];
        const float ss = __builtin_fmaf(t, t, p * p);   // p^2 + t^2
        const float pt = p * t;
        const f32x2 vs[4] = { {p,p}, {t,t}, {ss,ss}, {pt,pt} };
#pragma unroll
        for (int rp = 0; rp < 4; ++rp) {
            const int a = iy - 2 * rp;                      // compile-time
            if (a < 0 || a > 11) continue;                  // both lanes zero
            const float w0 = (a <= 10) ? WG[a] : 0.f;       // row 2rp
            const float w1 = (a >= 1)  ? WG[a - 1] : 0.f;   // row 2rp+1
            const f32x2 w = (f32x2){w0, w1};
#pragma unroll
            for (int m = 0; m < 4; ++m)
                A[m][rp] = __builtin_elementwise_fma(vs[m], w, A[m][rp]);
        }
    }

    // ---- horizontal pass: thread (rpl, g) -> out cols 4g..4g+3, row-pair rpl
    const int g   = tid & 127;         // col group
    const int rpl = tid >> 7;          // 0..3: row-pair slab this thread reads
    // write address: entry c = x+8
    const int wat = (x + 8) >> 1;
    const int wof = pmap(wat) * 16 + ((x + 8) & 1) * 8;
    // read addresses: atoms 2g+1..2g+8 -> entries 4g+2..4g+17 (win[0..15]);
    // out col 4g+c needs entries 4g+c+3..4g+c+13 = win[c+1..c+11]
    int rof[8];
#pragma unroll
    for (int q = 0; q < 8; ++q) rof[q] = pmap(2 * g + 1 + q) * 16;

    f32x2 H[4][4];   // [map][col]
#pragma unroll
    for (int phase = 0; phase < 2; ++phase) {
        if (phase) __syncthreads();   // phase-0 reads done before overwrite
#pragma unroll
        for (int ml = 0; ml < 2; ++ml)
#pragma unroll
            for (int rp = 0; rp < 4; ++rp)
                *(f32x2*)(ldsraw + (ml * 4 + rp) * SLAB_BYTES + wof) =
                    A[phase * 2 + ml][rp];
        __syncthreads();              // also covers pad-zero init (phase 0)

#pragma unroll
        for (int ml = 0; ml < 2; ++ml) {
            const unsigned char* slab = ldsraw + (ml * 4 + rpl) * SLAB_BYTES;
            f32x2 win[16];
#pragma unroll
            for (int q = 0; q < 8; ++q) {
                const float4 v = *(const float4*)(slab + rof[q]);
                win[2 * q]     = (f32x2){v.x, v.y};
                win[2 * q + 1] = (f32x2){v.z, v.w};
            }
#pragma unroll
            for (int c = 0; c < 4; ++c) {
                f32x2 h = (f32x2){0.f, 0.f};
#pragma unroll
                for (int k = 0; k < 11; ++k) {
                    const f32x2 wk = (f32x2){WG[k], WG[k]};
                    h = __builtin_elementwise_fma(win[c + 1 + k], wk, h);
                }
                H[phase * 2 + ml][c] = h;
            }
        }
    }

    // ---- SSIM on 4 cols x 2 rows ----
    const float C1 = 1e-4f, C2 = 9e-4f;
    float lsum = 0.f;
#pragma unroll
    for (int c = 0; c < 4; ++c) {
        const f32x2 mu1 = H[0][c], mu2 = H[1][c];
        const f32x2 S   = H[2][c], P  = H[3][c];
        const f32x2 mu12 = mu1 * mu2;
        const f32x2 musq = mu1 * mu1 + mu2 * mu2;
        // num = (2*mu1mu2 + C1) * (2*sigma12 + C2), sigma12 = P - mu12
        const f32x2 num = (mu12 + mu12 + (f32x2){C1, C1}) *
                          ((P - mu12) + (P - mu12) + (f32x2){C2, C2});
        // den = (musq + C1) * (S - musq + C2) + 1e-8
        const f32x2 den = (musq + (f32x2){C1, C1}) *
                          (S - musq + (f32x2){C2, C2}) + (f32x2){1e-8f, 1e-8f};
        lsum += num.x * __builtin_amdgcn_rcpf(den.x);
        lsum += num.y * __builtin_amdgcn_rcpf(den.y);
    }

    // ---- reduction: wave shuffle -> LDS -> one atomic per block (64 slots) ----
#pragma unroll
    for (int off = 32; off > 0; off >>= 1)
        lsum += __shfl_down(lsum, off);
    if ((tid & 63) == 0) wsum[tid >> 6] = lsum;
    __syncthreads();
    if (tid == 0) {
        float s = 0.f;
#pragma unroll
        for (int i = 0; i < 8; ++i) s += wsum[i];
        atomicAdd(&acc[blockIdx.x & (NACC - 1)], (double)s);
    }
}

__global__ void ssim_final(const double* __restrict__ acc, float* __restrict__ out) {
    double s = 0.0;
#pragma unroll
    for (int i = 0; i < NACC; ++i) s += acc[i];
    out[0] = 1.0f - (float)(s * (1.0 / (double)NPIX));
}

extern "C" void kernel_launch(void* const* d_in, const int* in_sizes, int n_in,
                              void* d_out, int out_size, void* d_ws, size_t ws_size,
                              hipStream_t stream) {
    const float* pred = (const float*)d_in[0];
    const float* targ = (const float*)d_in[1];
    double* acc = (double*)d_ws;

    hipMemsetAsync(acc, 0, NACC * sizeof(double), stream);

    dim3 grid(IMG_H / TY, PLANES);   // adjacent strips -> halo L2 reuse (R1: 219 MB)
    ssim_main<<<grid, 512, 0, stream>>>(pred, targ, acc);
    ssim_final<<<1, 1, 0, stream>>>(acc, (float*)d_out);
}